// Round 3
// baseline (17925.842 us; speedup 1.0000x reference)
//
#include <hip/hip_runtime.h>
#include <hip/hip_fp16.h>

typedef _Float16 f16x8 __attribute__((ext_vector_type(8)));
typedef float f32x4 __attribute__((ext_vector_type(4)));

#define NT 128      // 2 waves per block
#define B_ 256
#define D_ 128
#define T_ 512
#define H_ 512

#define NG 8        // batch groups
#define CB 32       // blocks per group
#define BS 32       // batch per group
#define HS 16       // h-cols per block
#define DS 4        // z-dims per block
#define PITCH 520   // f16 row pitch (1040 B -> 2-way bank aliasing = free)
#define GHSZ (NG * BS * H_)      // 131072 elems per h buffer

#define SC  2048.0f              // 2^11 prescale (keeps all f16 operands normal)
#define S1  (1.0f/2048.0f)       // 2^-11
#define S2  (1.0f/4194304.0f)    // 2^-22

#define MFMA16(A,B,C) __builtin_amdgcn_mfma_f32_16x16x32_f16((A),(B),(C),0,0,0)

// ---------------- setup: M = W_ih @ fc_W, split hi/lo(x2^11), lo tiled ------
__global__ __launch_bounds__(256)
void msd_setup_M(const float* __restrict__ W_ih, const float* __restrict__ fc_W,
                 _Float16* __restrict__ Mhi,   // [3H][H] plain
                 _Float16* __restrict__ Mlo)   // fragment-tiled, x2^11
{
    const int r0 = (blockIdx.x >> 1) * 4;          // 4 rows per block
    const int k  = ((blockIdx.x & 1) << 8) + threadIdx.x;   // 0..511
    for (int rr = 0; rr < 4; ++rr) {
        const int R = r0 + rr;
        const float* wrow = W_ih + (size_t)R * D_;
        float s = 0.0f;
        for (int d = 0; d < D_; ++d) s = fmaf(wrow[d], fc_W[(size_t)d * H_ + k], s);
        _Float16 hi = (_Float16)s;
        _Float16 lo = (_Float16)((s - (float)hi) * SC);
        Mhi[(size_t)R * H_ + k] = hi;
        const int t = R >> 9, jj = R & 511;
        const int c = jj >> 4, l16 = jj & 15;
        const int kt = k >> 5, quad = (k >> 3) & 3, j = k & 7;
        const size_t off = ((size_t)(((c * 3 + t) * 16 + kt) * 16 + l16) * 4 + quad) * 8 + j;
        Mlo[off] = lo;
    }
}

// ---------------- main persistent GRU scan ---------------------------------
__global__ __launch_bounds__(NT)
void msd_gru_kernel(const float* __restrict__ zin,
                    const float* __restrict__ W_ih,
                    const float* __restrict__ W_hh,
                    const float* __restrict__ b_ih,
                    const float* __restrict__ b_hh,
                    const float* __restrict__ fc_W,
                    const float* __restrict__ fc_b,
                    float* __restrict__ out,
                    _Float16* __restrict__ h1_g,     // 2 x [NG][BS][H_]  (h x 2^11)
                    _Float16* __restrict__ h2_g,     // 2 x [NG][BS][H_]  (resid x 2^22)
                    const _Float16* __restrict__ Mhi_w,   // [3H][H]
                    const _Float16* __restrict__ Mlo_w,   // tiled
                    unsigned* __restrict__ cnt)
{
    const int g   = blockIdx.x & 7;
    const int c   = blockIdx.x >> 3;
    const int B0  = g * BS;
    const int j0  = c * HS;
    const int d0  = c * DS;

    const int tid  = threadIdx.x;
    const int wave = tid >> 6;
    const int lane = tid & 63;
    const int l16  = lane & 15;
    const int quad = lane >> 4;
    const int bm0  = wave * 16;

    // LDS: (48*3 + 5) * 520 * 2 B = 154,960 B
    __shared__ __attribute__((aligned(16))) _Float16 Whh_s [48 * PITCH];
    __shared__ __attribute__((aligned(16))) _Float16 WhhL_s[48 * PITCH];  // x2^11
    __shared__ __attribute__((aligned(16))) _Float16 Mhi_s [48 * PITCH];
    __shared__ __attribute__((aligned(16))) _Float16 fcW_s [5 * PITCH];   // row 4 = zeros

    // ===== phase 0: z0 into scratch (reuse Mhi_s region), bootstrap state ====
    float* z0s = (float*)Mhi_s;   // 16 KB < 49.9 KB
    for (int idx = tid; idx < BS * D_; idx += NT) {
        int b = idx >> 7, d = idx & (D_ - 1);
        z0s[idx] = zin[(size_t)(B0 + b) * (D_ * T_) + (size_t)d * T_];
    }
    __syncthreads();

    f32x4 zfrag;
    #pragma unroll
    for (int e = 0; e < 4; ++e)
        zfrag[e] = (l16 < DS) ? z0s[(bm0 + quad * 4 + e) * D_ + d0 + l16] : 0.0f;
    if (l16 < DS) {
        #pragma unroll
        for (int e = 0; e < 4; ++e)
            out[(size_t)(B0 + bm0 + quad * 4 + e) * (D_ * T_) + (size_t)(d0 + l16) * T_] = zfrag[e];
    }
    // gi_1 = W_ih @ z0 + b_ih (exact fp32); c = W_ih @ fc_b; b_hh per lane
    f32x4 gi_st[3];
    float bhh_l[3], c_l[3];
    for (int t = 0; t < 3; ++t) {
        const int gr = t * H_ + j0 + l16;
        const float* wrow = W_ih + (size_t)gr * D_;
        bhh_l[t] = b_hh[gr];
        float s[4] = {b_ih[gr], b_ih[gr], b_ih[gr], b_ih[gr]};
        float cc = 0.0f;
        for (int d = 0; d < D_; ++d) {
            float wv = wrow[d];
            cc = fmaf(wv, fc_b[d], cc);
            #pragma unroll
            for (int e = 0; e < 4; ++e)
                s[e] = fmaf(wv, z0s[(bm0 + quad * 4 + e) * D_ + d], s[e]);
        }
        c_l[t] = cc;
        #pragma unroll
        for (int e = 0; e < 4; ++e) gi_st[t][e] = s[e];
    }
    const float fcb_l = (l16 < DS) ? fc_b[d0 + l16] : 0.0f;
    __syncthreads();   // z0s dead -> Mhi_s region reusable

    // ===== phase 1: stage weights (hi fp16 + lo fp16 x2^11) ==================
    for (int idx = tid; idx < 48 * H_; idx += NT) {
        int r = idx >> 9, k = idx & (H_ - 1);
        int gr = (r >> 4) * H_ + j0 + (r & 15);
        float w = W_hh[(size_t)gr * H_ + k];
        _Float16 hi = (_Float16)w;
        Whh_s [r * PITCH + k] = hi;
        WhhL_s[r * PITCH + k] = (_Float16)((w - (float)hi) * SC);
        Mhi_s [r * PITCH + k] = Mhi_w[(size_t)gr * H_ + k];
    }
    for (int idx = tid; idx < 5 * H_; idx += NT) {
        int r = idx >> 9, k = idx & (H_ - 1);
        float v = (r < DS) ? fc_W[(size_t)(d0 + r) * H_ + k] : 0.0f;
        fcW_s[r * PITCH + k] = (_Float16)v;
    }
    __syncthreads();

    float h_own[4] = {0.f, 0.f, 0.f, 0.f};
    unsigned* cg = cnt + g * 64;
    const int fcrow = (l16 < DS) ? l16 : 4;
    // M_lo tiled per-t lane base for this block/lane
    int mtb[3];
    #pragma unroll
    for (int t = 0; t < 3; ++t) mtb[t] = ((c * 3 + t) * 16) * 512 + (l16 * 4 + quad) * 8;

    for (int i = 1; i <= T_; ++i) {
        const size_t rb = (size_t)((i - 1) & 1) * GHSZ + (size_t)g * (BS * H_);
        const size_t wb = (size_t)(i & 1) * GHSZ + (size_t)g * (BS * H_);
        const _Float16* rh1 = h1_g + rb;
        const _Float16* rh2 = h2_g + rb;

        f32x4 acc_gh[3], acc2_gh[3], accM1[3], acc2_gi[3], acc_fc, acc2_fc;
        {
            f32x4 z4 = {0.f, 0.f, 0.f, 0.f};
            #pragma unroll
            for (int t = 0; t < 3; ++t) { acc_gh[t] = z4; acc2_gh[t] = z4; accM1[t] = z4; acc2_gi[t] = z4; }
            acc_fc = z4; acc2_fc = z4;
        }

        const size_t abase = (size_t)(bm0 + l16) * H_ + quad * 8;
        #pragma unroll 2
        for (int kt = 0; kt < 16; ++kt) {
            const int k0   = kt * 32;
            const int boff = k0 + quad * 8;
            f16x8 Ah = *(const f16x8*)(rh1 + abase + k0);   // h x 2^11
            f16x8 Al = *(const f16x8*)(rh2 + abase + k0);   // resid x 2^22
            #pragma unroll
            for (int t = 0; t < 3; ++t) {
                const int row = (t * 16 + l16) * PITCH + boff;
                f16x8 Bwh = *(const f16x8*)(Whh_s + row);
                f16x8 Bwl = *(const f16x8*)(WhhL_s + row);
                acc_gh[t]  = MFMA16(Ah, Bwh, acc_gh[t]);    // scale 2^11
                acc2_gh[t] = MFMA16(Al, Bwh, acc2_gh[t]);   // scale 2^22
                acc2_gh[t] = MFMA16(Ah, Bwl, acc2_gh[t]);   // scale 2^22
                f16x8 Bmh = *(const f16x8*)(Mhi_s + row);
                f16x8 Bml = *(const f16x8*)(Mlo_w + mtb[t] + kt * 512);
                accM1[t]   = MFMA16(Ah, Bmh, accM1[t]);
                acc2_gi[t] = MFMA16(Al, Bmh, acc2_gi[t]);
                acc2_gi[t] = MFMA16(Ah, Bml, acc2_gi[t]);
            }
            f16x8 Bf = *(const f16x8*)(fcW_s + fcrow * PITCH + boff);
            acc_fc  = MFMA16(Ah, Bf, acc_fc);
            acc2_fc = MFMA16(Al, Bf, acc2_fc);
        }

        if (i >= 2) {
            #pragma unroll
            for (int t = 0; t < 3; ++t)
                #pragma unroll
                for (int e = 0; e < 4; ++e)
                    gi_st[t][e] += accM1[t][e] * S1 + acc2_gi[t][e] * S2 + c_l[t];
            if (l16 < DS) {
                const int tcol = i - 1;
                #pragma unroll
                for (int e = 0; e < 4; ++e) {
                    zfrag[e] += acc_fc[e] * S1 + acc2_fc[e] * S2 + fcb_l;
                    out[(size_t)(B0 + bm0 + quad * 4 + e) * (D_ * T_) + (size_t)(d0 + l16) * T_ + tcol] = zfrag[e];
                }
            }
        }
        if (i <= T_ - 1) {
            _Float16* wh1 = h1_g + wb;
            _Float16* wh2 = h2_g + wb;
            #pragma unroll
            for (int e = 0; e < 4; ++e) {
                float ghr = acc_gh[0][e] * S1 + acc2_gh[0][e] * S2 + bhh_l[0];
                float ghz = acc_gh[1][e] * S1 + acc2_gh[1][e] * S2 + bhh_l[1];
                float ghn = acc_gh[2][e] * S1 + acc2_gh[2][e] * S2 + bhh_l[2];
                float r  = 1.0f / (1.0f + expf(-(gi_st[0][e] + ghr)));
                float zg = 1.0f / (1.0f + expf(-(gi_st[1][e] + ghz)));
                float xn = gi_st[2][e] + r * ghn;
                float hn = (1.0f - zg) * tanhf(xn) + zg * h_own[e];
                h_own[e] = hn;
                const size_t o = (size_t)(bm0 + quad * 4 + e) * H_ + j0 + l16;
                float hs = hn * SC;
                _Float16 a1 = (_Float16)hs;
                wh1[o] = a1;
                wh2[o] = (_Float16)((hs - (float)a1) * SC);
            }
            // group barrier: release stores, arrive, spin, acquire
            __threadfence();
            __syncthreads();
            if (tid == 0) {
                __hip_atomic_fetch_add(cg, 1u, __ATOMIC_RELEASE, __HIP_MEMORY_SCOPE_AGENT);
                const unsigned target = (unsigned)(CB * i);
                while (__hip_atomic_load(cg, __ATOMIC_ACQUIRE, __HIP_MEMORY_SCOPE_AGENT) < target)
                    __builtin_amdgcn_s_sleep(1);
            }
            __syncthreads();
            __threadfence();
        }
    }
}

extern "C" void kernel_launch(void* const* d_in, const int* in_sizes, int n_in,
                              void* d_out, int out_size, void* d_ws, size_t ws_size,
                              hipStream_t stream) {
    const float* z    = (const float*)d_in[0];
    // d_in[1] = e : unused by the reference computation
    const float* W_ih = (const float*)d_in[2];
    const float* W_hh = (const float*)d_in[3];
    const float* b_ih = (const float*)d_in[4];
    const float* b_hh = (const float*)d_in[5];
    const float* fc_W = (const float*)d_in[6];
    const float* fc_b = (const float*)d_in[7];
    float* out = (float*)d_out;

    // ws: [0,4K) counters | h1 2x | h2 2x | Mhi | Mlo(tiled)
    char* w = (char*)d_ws;
    unsigned* cnt = (unsigned*)w;
    _Float16* h1  = (_Float16*)(w + 4096);
    _Float16* h2  = (_Float16*)(w + 4096 + (size_t)4 * GHSZ);
    _Float16* Mhi = (_Float16*)(w + 4096 + (size_t)8 * GHSZ);
    _Float16* Mlo = (_Float16*)(w + 4096 + (size_t)8 * GHSZ + (size_t)3 * H_ * H_ * 2);

    // zero counters + h buffers (h_0 = 0); ws re-poisoned before every launch
    hipMemsetAsync(d_ws, 0, 4096 + (size_t)8 * GHSZ, stream);

    hipLaunchKernelGGL(msd_setup_M, dim3(768), dim3(256), 0, stream, W_ih, fc_W, Mhi, Mlo);
    hipLaunchKernelGGL(msd_gru_kernel, dim3(NG * CB), dim3(NT), 0, stream,
                       z, W_ih, W_hh, b_ih, b_hh, fc_W, fc_b, out, h1, h2, Mhi, Mlo, cnt);
}

// Round 4
// 5643.149 us; speedup vs baseline: 3.1766x; 3.1766x over previous
//
#include <hip/hip_runtime.h>
#include <hip/hip_fp16.h>

typedef _Float16 f16x8 __attribute__((ext_vector_type(8)));
typedef float f32x4 __attribute__((ext_vector_type(4)));
typedef unsigned long long u64;

#define NT 128      // 2 waves per block
#define B_ 256
#define D_ 128
#define T_ 512
#define H_ 512

#define NG 8        // batch groups (blockIdx&7 -> round-robin, likely same XCD)
#define CB 32       // blocks per group
#define BS 32       // batch per group
#define HS 16       // h-cols per block
#define DS 4        // z-dims per block
#define GHSZ (NG * BS * H_)      // 131072 elems per h buffer

#define SC  2048.0f              // 2^11 prescale (keeps all f16 operands normal)
#define S1  (1.0f/2048.0f)       // 2^-11
#define S2  (1.0f/4194304.0f)    // 2^-22

#define MFMA16(A,B,C) __builtin_amdgcn_mfma_f32_16x16x32_f16((A),(B),(C),0,0,0)
#define ALD(p)   __hip_atomic_load((p),  __ATOMIC_RELAXED, __HIP_MEMORY_SCOPE_AGENT)
#define AST(p,v) __hip_atomic_store((p),(v),__ATOMIC_RELAXED, __HIP_MEMORY_SCOPE_AGENT)

// ---------------- setup: M = W_ih @ fc_W, split hi/lo(x2^11), lo tiled ------
__global__ __launch_bounds__(256)
void msd_setup_M(const float* __restrict__ W_ih, const float* __restrict__ fc_W,
                 _Float16* __restrict__ Mhi,   // [3H][H] plain
                 _Float16* __restrict__ Mlo)   // fragment-tiled, x2^11
{
    const int r0 = (blockIdx.x >> 1) * 4;
    const int k  = ((blockIdx.x & 1) << 8) + threadIdx.x;
    for (int rr = 0; rr < 4; ++rr) {
        const int R = r0 + rr;
        const float* wrow = W_ih + (size_t)R * D_;
        float s = 0.0f;
        for (int d = 0; d < D_; ++d) s = fmaf(wrow[d], fc_W[(size_t)d * H_ + k], s);
        _Float16 hi = (_Float16)s;
        _Float16 lo = (_Float16)((s - (float)hi) * SC);
        Mhi[(size_t)R * H_ + k] = hi;
        const int t = R >> 9, jj = R & 511;
        const int c = jj >> 4, l16 = jj & 15;
        const int kt = k >> 5, quad = (k >> 3) & 3, j = k & 7;
        const size_t off = ((size_t)(((c * 3 + t) * 16 + kt) * 16 + l16) * 4 + quad) * 8 + j;
        Mlo[off] = lo;
    }
}

// ---------------- main persistent GRU scan ---------------------------------
__global__ __launch_bounds__(NT)
void msd_gru_kernel(const float* __restrict__ zin,
                    const float* __restrict__ W_ih,
                    const float* __restrict__ W_hh,
                    const float* __restrict__ b_ih,
                    const float* __restrict__ b_hh,
                    const float* __restrict__ fc_W,
                    const float* __restrict__ fc_b,
                    float* __restrict__ out,
                    unsigned short* __restrict__ h1_g,   // 2 x [NG][BS][H_] (h x 2^11, f16 bits)
                    unsigned short* __restrict__ h2_g,   // 2 x [NG][BS][H_] (resid x 2^22)
                    const _Float16* __restrict__ Mhi_w,  // [3H][H]
                    const _Float16* __restrict__ Mlo_w,  // tiled
                    unsigned* __restrict__ cnt)
{
    const int g   = blockIdx.x & 7;
    const int c   = blockIdx.x >> 3;
    const int B0  = g * BS;
    const int j0  = c * HS;
    const int d0  = c * DS;

    const int tid  = threadIdx.x;
    const int wave = tid >> 6;
    const int lane = tid & 63;
    const int l16  = lane & 15;
    const int quad = lane >> 4;
    const int bm0  = wave * 16;

    // LDS: (48*3 + 5) * 512 * 2 B = 152,576 B.  B-fragments XOR-swizzled:
    // chunk cc (8 f16) of row r stored at cc^(r&7)  -> conflict-free b128 reads.
    __shared__ __attribute__((aligned(16))) _Float16 Whh_s [48 * 512];
    __shared__ __attribute__((aligned(16))) _Float16 WhhL_s[48 * 512];  // x2^11
    __shared__ __attribute__((aligned(16))) _Float16 Mhi_s [48 * 512];
    __shared__ __attribute__((aligned(16))) _Float16 fcW_s [5 * 512];   // row 4 = zeros

    // ===== phase 0: z0 into scratch (reuse Mhi_s region), bootstrap state ====
    float* z0s = (float*)Mhi_s;   // 16 KB < 48 KB
    for (int idx = tid; idx < BS * D_; idx += NT) {
        int b = idx >> 7, d = idx & (D_ - 1);
        z0s[idx] = zin[(size_t)(B0 + b) * (D_ * T_) + (size_t)d * T_];
    }
    __syncthreads();

    f32x4 zfrag;
    #pragma unroll
    for (int e = 0; e < 4; ++e)
        zfrag[e] = (l16 < DS) ? z0s[(bm0 + quad * 4 + e) * D_ + d0 + l16] : 0.0f;
    if (l16 < DS) {
        #pragma unroll
        for (int e = 0; e < 4; ++e)
            out[(size_t)(B0 + bm0 + quad * 4 + e) * (D_ * T_) + (size_t)(d0 + l16) * T_] = zfrag[e];
    }
    // gi_1 = W_ih @ z0 + b_ih (exact fp32); c = W_ih @ fc_b; b_hh per lane
    f32x4 gi_st[3];
    float bhh_l[3], c_l[3];
    for (int t = 0; t < 3; ++t) {
        const int gr = t * H_ + j0 + l16;
        const float* wrow = W_ih + (size_t)gr * D_;
        bhh_l[t] = b_hh[gr];
        float s[4] = {b_ih[gr], b_ih[gr], b_ih[gr], b_ih[gr]};
        float cc = 0.0f;
        for (int d = 0; d < D_; ++d) {
            float wv = wrow[d];
            cc = fmaf(wv, fc_b[d], cc);
            #pragma unroll
            for (int e = 0; e < 4; ++e)
                s[e] = fmaf(wv, z0s[(bm0 + quad * 4 + e) * D_ + d], s[e]);
        }
        c_l[t] = cc;
        #pragma unroll
        for (int e = 0; e < 4; ++e) gi_st[t][e] = s[e];
    }
    const float fcb_l = (l16 < DS) ? fc_b[d0 + l16] : 0.0f;
    __syncthreads();   // z0s dead -> Mhi_s region reusable

    // ===== phase 1: stage weights (hi fp16 + lo fp16 x2^11), swizzled ========
    for (int idx = tid; idx < 48 * H_; idx += NT) {
        int r = idx >> 9, k = idx & (H_ - 1);
        int gr = (r >> 4) * H_ + j0 + (r & 15);
        int ccn = k >> 3, j = k & 7;
        int pos = r * 512 + (((ccn ^ (r & 7)) << 3) | j);
        float w = W_hh[(size_t)gr * H_ + k];
        _Float16 hi = (_Float16)w;
        Whh_s [pos] = hi;
        WhhL_s[pos] = (_Float16)((w - (float)hi) * SC);
        Mhi_s [pos] = Mhi_w[(size_t)gr * H_ + k];
    }
    for (int idx = tid; idx < 5 * H_; idx += NT) {
        int r = idx >> 9, k = idx & (H_ - 1);
        int ccn = k >> 3, j = k & 7;
        int pos = r * 512 + (((ccn ^ (r & 7)) << 3) | j);
        float v = (r < DS) ? fc_W[(size_t)(d0 + r) * H_ + k] : 0.0f;
        fcW_s[pos] = (_Float16)v;
    }
    __syncthreads();

    float h_own[4] = {0.f, 0.f, 0.f, 0.f};
    unsigned* cg = cnt + g * 64;
    const int fcrow = (l16 < DS) ? l16 : 4;
    int mtb[3];
    #pragma unroll
    for (int t = 0; t < 3; ++t) mtb[t] = ((c * 3 + t) * 16) * 512 + (l16 * 4 + quad) * 8;

    for (int i = 1; i <= T_; ++i) {
        const size_t rb = (size_t)((i - 1) & 1) * GHSZ + (size_t)g * (BS * H_);
        const size_t wb = (size_t)(i & 1) * GHSZ + (size_t)g * (BS * H_);
        const u64* rh1 = (const u64*)(h1_g + rb);
        const u64* rh2 = (const u64*)(h2_g + rb);

        f32x4 acc_gh[3], acc2_gh[3], accM1[3], acc2_gi[3], acc_fc;
        {
            f32x4 z4 = {0.f, 0.f, 0.f, 0.f};
            #pragma unroll
            for (int t = 0; t < 3; ++t) { acc_gh[t] = z4; acc2_gh[t] = z4; accM1[t] = z4; acc2_gi[t] = z4; }
            acc_fc = z4;
        }

        // A-fragment base in u64 units: ((bm0+l16)*H_ + quad*8) f16 = /4 u64
        const size_t a64 = ((size_t)(bm0 + l16) * H_ + quad * 8) >> 2;
        #pragma unroll 2
        for (int kt = 0; kt < 16; ++kt) {
            union { u64 q[2]; f16x8 v; } A1, A2;
            A1.q[0] = ALD(rh1 + a64 + kt * 8);
            A1.q[1] = ALD(rh1 + a64 + kt * 8 + 1);
            A2.q[0] = ALD(rh2 + a64 + kt * 8);
            A2.q[1] = ALD(rh2 + a64 + kt * 8 + 1);
            f16x8 Ah = A1.v;   // h x 2^11
            f16x8 Al = A2.v;   // resid x 2^22
            const int chunk = ((kt * 4 + quad) ^ (l16 & 7)) * 8;
            #pragma unroll
            for (int t = 0; t < 3; ++t) {
                const int row = (t * 16 + l16) * 512 + chunk;
                f16x8 Bwh = *(const f16x8*)(Whh_s + row);
                f16x8 Bwl = *(const f16x8*)(WhhL_s + row);
                acc_gh[t]  = MFMA16(Ah, Bwh, acc_gh[t]);    // scale 2^11
                acc2_gh[t] = MFMA16(Al, Bwh, acc2_gh[t]);   // scale 2^22
                acc2_gh[t] = MFMA16(Ah, Bwl, acc2_gh[t]);   // scale 2^22
                f16x8 Bmh = *(const f16x8*)(Mhi_s + row);
                f16x8 Bml = *(const f16x8*)(Mlo_w + mtb[t] + kt * 512);
                accM1[t]   = MFMA16(Ah, Bmh, accM1[t]);
                acc2_gi[t] = MFMA16(Al, Bmh, acc2_gi[t]);
                acc2_gi[t] = MFMA16(Ah, Bml, acc2_gi[t]);
            }
            f16x8 Bf = *(const f16x8*)(fcW_s + ((kt * 4 + quad) ^ (fcrow & 7)) * 8 + fcrow * 512);
            acc_fc = MFMA16(Ah, Bf, acc_fc);
        }

        if (i >= 2) {
            #pragma unroll
            for (int t = 0; t < 3; ++t)
                #pragma unroll
                for (int e = 0; e < 4; ++e)
                    gi_st[t][e] += accM1[t][e] * S1 + acc2_gi[t][e] * S2 + c_l[t];
            if (l16 < DS) {
                const int tcol = i - 1;
                #pragma unroll
                for (int e = 0; e < 4; ++e) {
                    zfrag[e] += acc_fc[e] * S1 + fcb_l;
                    out[(size_t)(B0 + bm0 + quad * 4 + e) * (D_ * T_) + (size_t)(d0 + l16) * T_ + tcol] = zfrag[e];
                }
            }
        }
        if (i <= T_ - 1) {
            unsigned short* wh1 = h1_g + wb;
            unsigned short* wh2 = h2_g + wb;
            #pragma unroll
            for (int e = 0; e < 4; ++e) {
                float ghr = acc_gh[0][e] * S1 + acc2_gh[0][e] * S2 + bhh_l[0];
                float ghz = acc_gh[1][e] * S1 + acc2_gh[1][e] * S2 + bhh_l[1];
                float ghn = acc_gh[2][e] * S1 + acc2_gh[2][e] * S2 + bhh_l[2];
                float r  = 1.0f / (1.0f + __expf(-(gi_st[0][e] + ghr)));
                float zg = 1.0f / (1.0f + __expf(-(gi_st[1][e] + ghz)));
                float xn = gi_st[2][e] + r * ghn;
                float hn = (1.0f - zg) * tanhf(xn) + zg * h_own[e];
                h_own[e] = hn;
                const size_t o = (size_t)(bm0 + quad * 4 + e) * H_ + j0 + l16;
                float hs = hn * SC;
                _Float16 a1 = (_Float16)hs;
                _Float16 a2 = (_Float16)((hs - (float)a1) * SC);
                union { _Float16 f; unsigned short u; } c1, c2;
                c1.f = a1; c2.f = a2;
                AST(wh1 + o, c1.u);   // relaxed agent-scope: at coherence point,
                AST(wh2 + o, c2.u);   // no cache-maintenance ops needed
            }
            // ---- group barrier, all-relaxed MI300 idiom ----
            // __syncthreads() drains each wave's vmcnt(0) before s_barrier, so
            // every wave's h-stores are at the coherence point before tid0 arrives.
            __syncthreads();
            if (tid == 0) {
                __hip_atomic_fetch_add(cg, 1u, __ATOMIC_RELAXED, __HIP_MEMORY_SCOPE_AGENT);
                const unsigned target = (unsigned)(CB * i);
                while (ALD(cg) < target) __builtin_amdgcn_s_sleep(1);
            }
            __syncthreads();
            // consumers read h via relaxed agent atomic loads -> always coherent
        }
    }
}

extern "C" void kernel_launch(void* const* d_in, const int* in_sizes, int n_in,
                              void* d_out, int out_size, void* d_ws, size_t ws_size,
                              hipStream_t stream) {
    const float* z    = (const float*)d_in[0];
    // d_in[1] = e : unused by the reference computation
    const float* W_ih = (const float*)d_in[2];
    const float* W_hh = (const float*)d_in[3];
    const float* b_ih = (const float*)d_in[4];
    const float* b_hh = (const float*)d_in[5];
    const float* fc_W = (const float*)d_in[6];
    const float* fc_b = (const float*)d_in[7];
    float* out = (float*)d_out;

    // ws: [0,4K) counters | h1 2x | h2 2x | Mhi | Mlo(tiled)
    char* w = (char*)d_ws;
    unsigned*       cnt = (unsigned*)w;
    unsigned short* h1  = (unsigned short*)(w + 4096);
    unsigned short* h2  = (unsigned short*)(w + 4096 + (size_t)4 * GHSZ);
    _Float16*       Mhi = (_Float16*)(w + 4096 + (size_t)8 * GHSZ);
    _Float16*       Mlo = (_Float16*)(w + 4096 + (size_t)8 * GHSZ + (size_t)3 * H_ * H_ * 2);

    // zero counters + h buffers (h_0 = 0); ws re-poisoned before every launch
    hipMemsetAsync(d_ws, 0, 4096 + (size_t)8 * GHSZ, stream);

    hipLaunchKernelGGL(msd_setup_M, dim3(768), dim3(256), 0, stream, W_ih, fc_W, Mhi, Mlo);
    hipLaunchKernelGGL(msd_gru_kernel, dim3(NG * CB), dim3(NT), 0, stream,
                       z, W_ih, W_hh, b_ih, b_hh, fc_W, fc_b, out, h1, h2, Mhi, Mlo, cnt);
}